// Round 15
// baseline (168.684 us; speedup 1.0000x reference)
//
#include <hip/hip_runtime.h>
#include <math.h>

#define NN 8192
#define CF 192
#define KNN 9
#define NSPL 4

typedef __bf16 v8bf __attribute__((ext_vector_type(8)));
typedef float f32x16 __attribute__((ext_vector_type(16)));
typedef float f32x4 __attribute__((ext_vector_type(4)));

__device__ __forceinline__ int group_start(int g) {
    // smallest i with batch[i]==g :  ceil(8191*g/8), capped at 8192
    int s = (8191 * g + 7) >> 3;
    return s > 8192 ? 8192 : s;
}

__device__ __forceinline__ float disf(int d) {
    return d > 0 ? 1.0f / sqrtf((float)d) : 0.0f;
}

__device__ __forceinline__ unsigned short f2bf(float f) {
    unsigned u = __float_as_uint(f);
    unsigned r = (u + 0x7FFFu + ((u >> 16) & 1u)) >> 16;   // round-nearest-even
    return (unsigned short)r;
}
__device__ __forceinline__ float bf2f(unsigned short h) {
    return __uint_as_float(((unsigned)h) << 16);
}

// ---------------------------------------------------------------- transpose + split + sq
// x [8,192,32,32] -> xh/xl [8192][192] bf16 (hi/lo split, computed once).
// One block owns 64 nodes x all 192 ch -> sq computed locally; deg zeroed.
__global__ __launch_bounds__(256) void transpose_kernel(
    const float* __restrict__ x, unsigned short* __restrict__ xh,
    unsigned short* __restrict__ xl, float* __restrict__ sq,
    int* __restrict__ deg)
{
    __shared__ float tile[32][65];
    int b = blockIdx.x, ht = blockIdx.y;         // 8 x 16 blocks
    int hw0 = ht * 64;
    int tid = threadIdx.x;
    if (tid < 64) deg[(b * 16 + ht) * 64 + tid] = 0;

    float sacc[8];
#pragma unroll
    for (int p = 0; p < 8; ++p) sacc[p] = 0.0f;

    for (int ct = 0; ct < 6; ++ct) {
        int c0 = ct * 32;
        __syncthreads();
#pragma unroll
        for (int p = 0; p < 8; ++p) {
            int c  = p * 4 + (tid >> 6);
            int hw = tid & 63;
            tile[c][hw] = x[(size_t)b * 196608 + (size_t)(c0 + c) * 1024 + hw0 + hw];
        }
        __syncthreads();
#pragma unroll
        for (int p = 0; p < 8; ++p) {
            int hw = p * 8 + (tid >> 5);
            int cc = tid & 31;
            float v = tile[cc][hw];
            size_t o = (size_t)(b * 1024 + hw0 + hw) * CF + c0 + cc;
            unsigned short h = f2bf(v);
            xh[o] = h;
            xl[o] = f2bf(v - bf2f(h));
            sacc[p] = fmaf(v, v, sacc[p]);
        }
    }
#pragma unroll
    for (int p = 0; p < 8; ++p) {
        float s = sacc[p];
#pragma unroll
        for (int off = 16; off > 0; off >>= 1) s += __shfl_xor(s, off, 32);
        if ((tid & 31) == 0)
            sq[(size_t)(b * 1024 + hw0 + p * 8 + (tid >> 5))] = s;
    }
}

// ---------------------------------------------------------------- kNN partial (MFMA, barrier-free K-loop)
// 576 blocks x 256 thr. Gram via split-bf16 32x32x16 MFMA (fp32-class err).
// K-loop has NO LDS staging and NO barriers: each lane's A/B fragment is 16
// contiguous bytes of a row-major row (row=lane&31, k=(lane>>5)*8+j), loaded
// DIRECTLY from global into operand VGPRs. Waves run decoupled; compiler
// pipelines loads across kb with fine vmcnt (the thing barrier-crossing
// register prefetch could never do — spilled in R5/R13). xh+xl = 6.3 MB
// lives in L2/L3; gather amplification ~2x is hidden by MFMAs.
// C/D layout (HW-verified): col=lane&31, row=(reg&3)+8*(reg>>2)+4*(lane>>5).
// Round-7 lesson: every acc index compile-time constant (unrolled loops).
__global__ __launch_bounds__(256, 2) void knn_kernel(
    const unsigned short* __restrict__ xh, const unsigned short* __restrict__ xl,
    const float* __restrict__ sq,
    float* __restrict__ pk_d, int* __restrict__ pk_i)
{
    int bid = blockIdx.x;
    int g = bid >> 6;
    int rem = bid & 63;
    int qb = rem >> 2;
    int split = rem & 3;
    int gs = group_start(g);
    int gsize = group_start(g + 1) - gs;
    int q0 = qb * 64;
    int nq = gsize - q0; if (nq > 64) nq = 64;
    if (nq <= 0) return;                 // block-uniform; q's covered elsewhere
    int c0 = split * 256;
    int ncc = gsize - c0; if (ncc > 256) ncc = 256;

    int tid = threadIdx.x;

    float td[KNN]; int ti[KNN];
#pragma unroll
    for (int j = 0; j < KNN; ++j) { td[j] = __builtin_inff(); ti[j] = -1; }

    if (ncc <= 0) {                      // block-uniform: empty split
        if (tid < nq) {
            int q = gs + q0 + tid;
            size_t base = ((size_t)q * NSPL + split) * KNN;
#pragma unroll
            for (int j = 0; j < KNN; ++j) { pk_d[base + j] = td[j]; pk_i[base + j] = ti[j]; }
        }
        return;
    }

    __shared__ float Ds[64][69];         // one 64-col quarter at a time (17664)
    __shared__ float ld[4][KNN][65];     // phase-1 sorted lists (9360)
    __shared__ int   li[4][KNN][65];     // (9360)
    __shared__ float sqc_s[256];
    __shared__ float sqq_s[64];

    int lane = tid & 63, w = tid >> 6;
    int k8 = (lane >> 5) * 8;

    if (tid < 64) {
        int qo = q0 + tid; if (qo > gsize - 1) qo = gsize - 1;
        sqq_s[tid] = sq[gs + qo];
    }
    {
        int co = c0 + tid;
        sqc_s[tid] = (tid < ncc) ? sq[gs + co] : __builtin_inff();
    }

    // fragment source pointers (fixed across kb; rows clamped like staging did)
    int aq = q0 + (w & 1) * 32 + (lane & 31);
    if (aq > gsize - 1) aq = gsize - 1;
    const unsigned short* ah_p = xh + (size_t)(gs + aq) * CF + k8;
    const unsigned short* al_p = xl + (size_t)(gs + aq) * CF + k8;
    const unsigned short* bh_p[4];
    const unsigned short* bl_p[4];
#pragma unroll
    for (int t = 0; t < 4; ++t) {
        int co = c0 + (w >> 1) * 128 + t * 32 + (lane & 31);
        if (co > gsize - 1) co = gsize - 1;
        bh_p[t] = xh + (size_t)(gs + co) * CF + k8;
        bl_p[t] = xl + (size_t)(gs + co) * CF + k8;
    }

    f32x16 acc[4];
#pragma unroll
    for (int t = 0; t < 4; ++t)
#pragma unroll
        for (int r = 0; r < 16; ++r) acc[t][r] = 0.0f;

#pragma unroll 2
    for (int kb = 0; kb < 12; ++kb) {
        int off = kb * 16;
        v8bf a_hi = *(const v8bf*)(ah_p + off);
        v8bf a_lo = *(const v8bf*)(al_p + off);
#pragma unroll
        for (int t = 0; t < 4; ++t) {
            v8bf b_hi = *(const v8bf*)(bh_p[t] + off);
            v8bf b_lo = *(const v8bf*)(bl_p[t] + off);
            acc[t] = __builtin_amdgcn_mfma_f32_32x32x16_bf16(a_hi, b_hi, acc[t], 0, 0, 0);
            acc[t] = __builtin_amdgcn_mfma_f32_32x32x16_bf16(a_lo, b_hi, acc[t], 0, 0, 0);
            acc[t] = __builtin_amdgcn_mfma_f32_32x32x16_bf16(a_hi, b_lo, acc[t], 0, 0, 0);
        }
    }

    // ---- selection over four 64-column quarters (candidates in index order)
#pragma unroll
    for (int qt = 0; qt < 4; ++qt) {
        __syncthreads();                 // Ds free / prev phase2 done
        if ((w >> 1) == (qt >> 1)) {
#pragma unroll
            for (int s = 0; s < 2; ++s) {
#pragma unroll
                for (int r = 0; r < 16; ++r) {
                    int row = (w & 1) * 32 + (r & 3) + 8 * (r >> 2) + 4 * (lane >> 5);
                    Ds[row][s * 32 + (lane & 31)] = acc[(qt & 1) * 2 + s][r];
                }
            }
        }
        __syncthreads();
        // phase1: thread -> (query q = tid&63, chunk ch = tid>>6 of 16 cands)
        {
            int q = tid & 63, ch = tid >> 6;
            float sqq = sqq_s[q];
            float pd[KNN]; int pi[KNN];
#pragma unroll
            for (int j = 0; j < KNN; ++j) { pd[j] = __builtin_inff(); pi[j] = -1; }
            for (int j16 = 0; j16 < 16; ++j16) {
                int c = ch * 16 + j16;
                float d = (sqq - 2.0f * Ds[q][c]) + sqc_s[qt * 64 + c];  // inf pad
                if (d < pd[KNN - 1]) {
                    pd[KNN - 1] = d; pi[KNN - 1] = gs + c0 + qt * 64 + c;
#pragma unroll
                    for (int j = KNN - 1; j > 0; --j) {
                        if (pd[j] < pd[j - 1]) {
                            float tf = pd[j]; pd[j] = pd[j - 1]; pd[j - 1] = tf;
                            int tn = pi[j]; pi[j] = pi[j - 1]; pi[j - 1] = tn;
                        }
                    }
                }
            }
#pragma unroll
            for (int j = 0; j < KNN; ++j) { ld[ch][j][q] = pd[j]; li[ch][j][q] = pi[j]; }
        }
        __syncthreads();
        // phase2: 64 threads merge 4 sorted lists (index order; early break)
        if (tid < 64) {
            for (int ch = 0; ch < 4; ++ch) {
#pragma unroll
                for (int j0 = 0; j0 < KNN; ++j0) {
                    float d = ld[ch][j0][tid];
                    if (!(d < td[KNN - 1])) break;   // sorted: rest can't insert
                    int id = li[ch][j0][tid];
                    td[KNN - 1] = d; ti[KNN - 1] = id;
#pragma unroll
                    for (int j = KNN - 1; j > 0; --j) {
                        if (td[j] < td[j - 1]) {
                            float tf = td[j]; td[j] = td[j - 1]; td[j - 1] = tf;
                            int tn = ti[j]; ti[j] = ti[j - 1]; ti[j - 1] = tn;
                        }
                    }
                }
            }
        }
    }

    if (tid < nq) {
        int q = gs + q0 + tid;
        size_t base = ((size_t)q * NSPL + split) * KNN;
#pragma unroll
        for (int j = 0; j < KNN; ++j) { pk_d[base + j] = td[j]; pk_i[base + j] = ti[j]; }
    }
}

// ---------------------------------------------------------------- merge + deg + W-transpose
// blocks 0..127: merge partial lists (64 q each). blocks 128..199: build
// bf16 W0^T/W1^T (n-major) into the dead xl region for out_kernel's MFMA
// B-fragments (fused here to avoid an extra dispatch).
__global__ __launch_bounds__(64) void merge_kernel(
    const float* __restrict__ pk_d, const int* __restrict__ pk_i,
    int* __restrict__ edges, int* __restrict__ deg,
    const float* __restrict__ W0, const float* __restrict__ W1,
    unsigned short* __restrict__ wt)
{
    __shared__ float wtile[32][33];
    int tid = threadIdx.x;
    if (blockIdx.x >= 128) {             // ---- W transpose path
        int wid = blockIdx.x - 128;      // 0..71
        int mat = wid / 36, rem2 = wid % 36;
        int k0 = (rem2 / 6) * 32, n0 = (rem2 % 6) * 32;
        const float* W = mat ? W1 : W0;
#pragma unroll
        for (int p = 0; p < 4; ++p) {
            int idx = p * 64 + tid;
            int k = idx >> 3, n4 = (idx & 7) * 4;
            *(float4*)&wtile[k][n4] =
                *(const float4*)(W + (size_t)(k0 + k) * CF + n0 + n4);
        }
        __syncthreads();
#pragma unroll
        for (int p = 0; p < 4; ++p) {
            int idx = p * 64 + tid;
            int n = idx >> 3, k4 = (idx & 7) * 4;
            ushort4 h;
            h.x = f2bf(wtile[k4 + 0][n]); h.y = f2bf(wtile[k4 + 1][n]);
            h.z = f2bf(wtile[k4 + 2][n]); h.w = f2bf(wtile[k4 + 3][n]);
            *(ushort4*)(wt + (size_t)mat * 36864 + (size_t)(n0 + n) * CF + k0 + k4) = h;
        }
        return;
    }
    int q = blockIdx.x * 64 + tid;
    float td[KNN]; int ti[KNN];
#pragma unroll
    for (int j = 0; j < KNN; ++j) { td[j] = __builtin_inff(); ti[j] = -1; }
    for (int s = 0; s < NSPL; ++s) {       // split order = index order (stable)
        size_t base = ((size_t)q * NSPL + s) * KNN;
#pragma unroll
        for (int j0 = 0; j0 < KNN; ++j0) {
            float d = pk_d[base + j0];
            if (!(d < td[KNN - 1])) break;   // lists sorted: rest can't insert
            int id = pk_i[base + j0];
            td[KNN - 1] = d; ti[KNN - 1] = id;
#pragma unroll
            for (int j = KNN - 1; j > 0; --j) {
                if (td[j] < td[j - 1]) {
                    float tf = td[j]; td[j] = td[j - 1]; td[j - 1] = tf;
                    int tn = ti[j]; ti[j] = ti[j - 1]; ti[j - 1] = tn;
                }
            }
        }
    }
#pragma unroll
    for (int j = 0; j < KNN; ++j) {
        int id = ti[j];                   // -1 <=> invalid (d == inf)
        edges[q * KNN + j] = id;
        if (id >= 0 && id != q) atomicAdd(&deg[id], 1);
    }
}

// ---------------------------------------------------------------- fused Tx1 + out GEMM (MFMA)
// One block per 16-row stripe (512 blocks). out = A0@W0 + A1@W1 + bias via
// mfma_f32_16x16x32_bf16, K=384 fused. A-frag: A[m=lane&15][k=quad*8+j]
// (row-major LDS, rows padded to 200 -> 2-way banks = free). B-frag:
// W^T[n=lane&15][k] row-major from the precomputed wt. C/D (m89-verified):
// col=lane&15, row=(lane>>4)*4+reg. Wave w owns n-tiles {3w..3w+2}.
__global__ __launch_bounds__(256, 2) void out_kernel(
    const unsigned short* __restrict__ xh, const unsigned short* __restrict__ wt,
    const int* __restrict__ edges, const int* __restrict__ deg,
    const float* __restrict__ bias, float* __restrict__ out)
{
    __shared__ unsigned short A0s[16][200];     // xf rows   (6400 B, padded)
    __shared__ unsigned short A1s[16][200];     // Tx1 rows  (6400 B, padded)
    __shared__ unsigned short Wts[2][CF][32];   // W^T k-slice (24576 B)
    __shared__ float coef_s[16][KNN];
    __shared__ int   nb_s[16][KNN];

    int r0 = blockIdx.x * 16;
    int tid = threadIdx.x;

    // stage xf rows (bf16 copy): 16 x 24 uint4 = 384
    for (int t = tid; t < 384; t += 256) {
        int i = t / 24, c8 = (t % 24) * 8;
        *(uint4*)&A0s[i][c8] = *(const uint4*)(xh + (size_t)(r0 + i) * CF + c8);
    }
    // coefficients: one (row, edge) per thread
    if (tid < 16 * KNN) {
        int i = tid / KNN, j = tid % KNN;
        int q = r0 + i;
        int id = edges[q * KNN + j];
        float cf = 0.0f; int s = q;
        if (id >= 0 && id != q) { cf = -disf(deg[id]) * disf(deg[q]); s = id; }
        coef_s[i][j] = cf; nb_s[i][j] = s;
    }
    __syncthreads();
    // gather Tx1 rows from bf16 -> bf16 pairs: 1536 pairs
    for (int e = tid; e < 16 * CF / 2; e += 256) {
        int i = e / 96, c2 = (e % 96) * 2;
        float a0 = 0.0f, a1 = 0.0f;
#pragma unroll
        for (int t = 0; t < KNN; ++t) {
            const unsigned short* row = xh + (size_t)nb_s[i][t] * CF + c2;
            float cf = coef_s[i][t];
            a0 = fmaf(cf, bf2f(row[0]), a0);
            a1 = fmaf(cf, bf2f(row[1]), a1);
        }
        ushort2 h; h.x = f2bf(a0); h.y = f2bf(a1);
        *(ushort2*)&A1s[i][c2] = h;
    }

    int lane = tid & 63, w = tid >> 6;
    int m = lane & 15;                   // A row / B col index
    int kq = (lane >> 4) * 8;            // k offset within 32-slice
    f32x4 acc[3];
#pragma unroll
    for (int t = 0; t < 3; ++t)
#pragma unroll
        for (int r = 0; r < 4; ++r) acc[t][r] = 0.0f;

    for (int kt = 0; kt < 6; ++kt) {     // K=192 in 32-slices, both mats fused
        __syncthreads();                 // kt=0: A1s ready; else Wts consumed
#pragma unroll
        for (int p = 0; p < 6; ++p) {    // stage Wts: 1536 uint4
            int f = p * 256 + tid;
            int mat = f / 768, n = (f % 768) / 4, k16 = (f % 4) * 8;
            *(uint4*)&Wts[mat][n][k16] =
                *(const uint4*)(wt + (size_t)mat * 36864 + (size_t)n * CF + kt * 32 + k16);
        }
        __syncthreads();
        v8bf a0 = *(const v8bf*)&A0s[m][kt * 32 + kq];
        v8bf a1 = *(const v8bf*)&A1s[m][kt * 32 + kq];
#pragma unroll
        for (int t3 = 0; t3 < 3; ++t3) {
            int n0 = w * 48 + t3 * 16;
            v8bf w0 = *(const v8bf*)&Wts[0][n0 + m][kq];
            v8bf w1 = *(const v8bf*)&Wts[1][n0 + m][kq];
            acc[t3] = __builtin_amdgcn_mfma_f32_16x16x32_bf16(a0, w0, acc[t3], 0, 0, 0);
            acc[t3] = __builtin_amdgcn_mfma_f32_16x16x32_bf16(a1, w1, acc[t3], 0, 0, 0);
        }
    }

    int col = lane & 15, rb = (lane >> 4) * 4;
#pragma unroll
    for (int t3 = 0; t3 < 3; ++t3) {
        int n0 = w * 48 + t3 * 16;
        float bv = bias[n0 + col];
#pragma unroll
        for (int r = 0; r < 4; ++r)
            out[(size_t)(r0 + rb + r) * CF + n0 + col] = acc[t3][r] + bv;
    }
}

// ---------------------------------------------------------------- launch
extern "C" void kernel_launch(void* const* d_in, const int* in_sizes, int n_in,
                              void* d_out, int out_size, void* d_ws, size_t ws_size,
                              hipStream_t stream)
{
    const float* x    = (const float*)d_in[0];
    const float* W0   = (const float*)d_in[1];
    const float* W1   = (const float*)d_in[2];
    const float* bias = (const float*)d_in[3];
    float* out = (float*)d_out;

    // Workspace: 6,651,904 B (known-safe total).
    char* ws = (char*)d_ws;
    unsigned short* xh = (unsigned short*)ws; ws += (size_t)NN * CF * 2;  // 3,145,728
    unsigned short* xl = (unsigned short*)ws; ws += (size_t)NN * CF * 2;  // 3,145,728
    float* sq    = (float*)ws;  ws += (size_t)NN * 4;        //    32,768
    int*   deg   = (int*)ws;    ws += (size_t)NN * 4;        //    32,768
    int*   edges = (int*)ws;    ws += (size_t)NN * KNN * 4;  //   294,912

    // xl is dead after knn -> reuse its space for bf16 W0^T/W1^T (147 KB).
    unsigned short* wt = xl;

    // Partial top-k lists live in d_out (2.36 MB of its 6.29 MB); d_out is
    // fully overwritten by out_kernel afterwards, every call.
    float* pk_d = out;                                       // NN*NSPL*KNN
    int*   pk_i = (int*)(out + (size_t)NN * NSPL * KNN);     // NN*NSPL*KNN

    hipLaunchKernelGGL(transpose_kernel, dim3(8, 16), dim3(256), 0, stream,
                       x, xh, xl, sq, deg);
    hipLaunchKernelGGL(knn_kernel, dim3(576), dim3(256), 0, stream,
                       xh, xl, sq, pk_d, pk_i);
    hipLaunchKernelGGL(merge_kernel, dim3(200), dim3(64), 0, stream,
                       pk_d, pk_i, edges, deg, W0, W1, wt);
    hipLaunchKernelGGL(out_kernel, dim3(512), dim3(256), 0, stream,
                       xh, wt, edges, deg, bias, out);
}

// Round 16
// 144.149 us; speedup vs baseline: 1.1702x; 1.1702x over previous
//
#include <hip/hip_runtime.h>
#include <math.h>

#define NN 8192
#define CF 192
#define KNN 9
#define NSPL 8

typedef __bf16 v8bf __attribute__((ext_vector_type(8)));
typedef float f32x16 __attribute__((ext_vector_type(16)));
typedef float f32x4 __attribute__((ext_vector_type(4)));

__device__ __forceinline__ int group_start(int g) {
    // smallest i with batch[i]==g :  ceil(8191*g/8), capped at 8192
    int s = (8191 * g + 7) >> 3;
    return s > 8192 ? 8192 : s;
}

__device__ __forceinline__ float disf(int d) {
    return d > 0 ? 1.0f / sqrtf((float)d) : 0.0f;
}

__device__ __forceinline__ unsigned short f2bf(float f) {
    unsigned u = __float_as_uint(f);
    unsigned r = (u + 0x7FFFu + ((u >> 16) & 1u)) >> 16;   // round-nearest-even
    return (unsigned short)r;
}
__device__ __forceinline__ float bf2f(unsigned short h) {
    return __uint_as_float(((unsigned)h) << 16);
}

// ---------------------------------------------------------------- transpose + split + sq
// x [8,192,32,32] -> xh/xl [8192][192] bf16 (hi/lo split, computed once).
// One block owns 64 nodes x all 192 ch -> sq computed locally; deg zeroed.
__global__ __launch_bounds__(256) void transpose_kernel(
    const float* __restrict__ x, unsigned short* __restrict__ xh,
    unsigned short* __restrict__ xl, float* __restrict__ sq,
    int* __restrict__ deg)
{
    __shared__ float tile[32][65];
    int b = blockIdx.x, ht = blockIdx.y;         // 8 x 16 blocks
    int hw0 = ht * 64;
    int tid = threadIdx.x;
    if (tid < 64) deg[(b * 16 + ht) * 64 + tid] = 0;

    float sacc[8];
#pragma unroll
    for (int p = 0; p < 8; ++p) sacc[p] = 0.0f;

    for (int ct = 0; ct < 6; ++ct) {
        int c0 = ct * 32;
        __syncthreads();
#pragma unroll
        for (int p = 0; p < 8; ++p) {
            int c  = p * 4 + (tid >> 6);
            int hw = tid & 63;
            tile[c][hw] = x[(size_t)b * 196608 + (size_t)(c0 + c) * 1024 + hw0 + hw];
        }
        __syncthreads();
#pragma unroll
        for (int p = 0; p < 8; ++p) {
            int hw = p * 8 + (tid >> 5);
            int cc = tid & 31;
            float v = tile[cc][hw];
            size_t o = (size_t)(b * 1024 + hw0 + hw) * CF + c0 + cc;
            unsigned short h = f2bf(v);
            xh[o] = h;
            xl[o] = f2bf(v - bf2f(h));
            sacc[p] = fmaf(v, v, sacc[p]);
        }
    }
#pragma unroll
    for (int p = 0; p < 8; ++p) {
        float s = sacc[p];
#pragma unroll
        for (int off = 16; off > 0; off >>= 1) s += __shfl_xor(s, off, 32);
        if ((tid & 31) == 0)
            sq[(size_t)(b * 1024 + hw0 + p * 8 + (tid >> 5))] = s;
    }
}

// ---------------------------------------------------------------- kNN partial (MFMA)
// grid: 9 groups x 16 query-blocks(64 q) x 8 candidate-splits(128 c) = 1152
// blocks = 4.5/CU (R12/R14's 576-block grid was GRID-limited at 2.25/CU).
// LDS ~29 KB (Ds + phase-1 lists overlay the dead staging region).
// Gram via split-bf16 32x32x16 MFMA, direct load->LDS staging (register
// prefetch spilled in R5/R13; direct-from-global operands TA-serialized in
// R15 — coalesced LDS staging is the proven shape).
// C/D layout (HW-verified): col=lane&31, row=(reg&3)+8*(reg>>2)+4*(lane>>5).
// Round-7 lesson: every acc index compile-time constant (unrolled loops).
__global__ __launch_bounds__(256, 2) void knn_kernel(
    const unsigned short* __restrict__ xh, const unsigned short* __restrict__ xl,
    const float* __restrict__ sq,
    float* __restrict__ pk_d, int* __restrict__ pk_i)
{
    int bid = blockIdx.x;
    int g = bid >> 7;
    int rem = bid & 127;
    int qb = rem >> 3;
    int split = rem & 7;
    int gs = group_start(g);
    int gsize = group_start(g + 1) - gs;
    int q0 = qb * 64;
    int nq = gsize - q0; if (nq > 64) nq = 64;
    if (nq <= 0) return;                 // block-uniform; q's covered elsewhere
    int c0 = split * 128;
    int ncc = gsize - c0; if (ncc > 128) ncc = 128;

    int tid = threadIdx.x;

    float td[KNN]; int ti[KNN];
#pragma unroll
    for (int j = 0; j < KNN; ++j) { td[j] = __builtin_inff(); ti[j] = -1; }

    if (ncc <= 0) {                      // block-uniform: empty split
        if (tid < nq) {
            int q = gs + q0 + tid;
            size_t base = ((size_t)q * NSPL + split) * KNN;
#pragma unroll
            for (int j = 0; j < KNN; ++j) { pk_d[base + j] = td[j]; pk_i[base + j] = ti[j]; }
        }
        return;
    }

    // staging region (18432 B) overlaid by lists+Ds (28192 B) after K-loop
    __shared__ __align__(16) char smem[28192];
    unsigned short (*Ah)[24] = (unsigned short(*)[24])smem;            // 64x24x2  = 3072
    unsigned short (*Al)[24] = (unsigned short(*)[24])(smem + 3072);   // 3072
    unsigned short (*Bh)[24] = (unsigned short(*)[24])(smem + 6144);   // 128x24x2 = 6144
    unsigned short (*Bl)[24] = (unsigned short(*)[24])(smem + 12288);  // 6144
    float (*ld)[KNN][65] = (float(*)[KNN][65])smem;                    // 4x9x65x4 = 9360
    int   (*li)[KNN][65] = (int(*)[KNN][65])(smem + 9360);             // 9360
    float (*Ds)[37] = (float(*)[37])(smem + 18720);                    // 64x37x4 = 9472
    __shared__ float sqc_s[128];
    __shared__ float sqq_s[64];

    int lane = tid & 63, w = tid >> 6;
    int arow = (w & 1) * 32 + (lane & 31);
    int k8 = (lane >> 5) * 8;
    int brow0 = (w >> 1) * 64 + (lane & 31);

    if (tid < 64) {
        int qo = q0 + tid; if (qo > gsize - 1) qo = gsize - 1;
        sqq_s[tid] = sq[gs + qo];
    }
    if (tid < 128) {
        sqc_s[tid] = (tid < ncc) ? sq[gs + c0 + tid] : __builtin_inff();
    }

    // per-thread staging roles (fixed across kb)
    int a_hl = tid >> 7, a_r = (tid >> 1) & 63, a_half = tid & 1;
    int a_qo = q0 + a_r; if (a_qo > gsize - 1) a_qo = gsize - 1;
    const unsigned short* a_src = (a_hl ? xl : xh)
        + (size_t)(gs + a_qo) * CF + a_half * 8;
    unsigned short* a_dst = (a_hl ? (unsigned short*)Al : (unsigned short*)Ah)
        + a_r * 24 + a_half * 8;

    f32x16 acc[2];
#pragma unroll
    for (int t = 0; t < 2; ++t)
#pragma unroll
        for (int r = 0; r < 16; ++r) acc[t][r] = 0.0f;

    for (int kb = 0; kb < 12; ++kb) {
        __syncthreads();
        *(uint4*)a_dst = *(const uint4*)(a_src + kb * 16);   // A hi/lo copy
#pragma unroll
        for (int p = 0; p < 2; ++p) {    // B tiles: 512 x 16B copies
            int t = tid + 256 * p;
            int hl = t >> 8, r = (t >> 1) & 127, half = t & 1;
            int co = c0 + r; if (co > gsize - 1) co = gsize - 1;
            const unsigned short* src = (hl ? xl : xh)
                + (size_t)(gs + co) * CF + kb * 16 + half * 8;
            unsigned short* dst = (hl ? (unsigned short*)Bl : (unsigned short*)Bh)
                + r * 24 + half * 8;
            *(uint4*)dst = *(const uint4*)src;
        }
        __syncthreads();
        v8bf a_hi = *(const v8bf*)&Ah[arow][k8];
        v8bf a_lo = *(const v8bf*)&Al[arow][k8];
#pragma unroll
        for (int t = 0; t < 2; ++t) {
            v8bf b_hi = *(const v8bf*)&Bh[brow0 + t * 32][k8];
            v8bf b_lo = *(const v8bf*)&Bl[brow0 + t * 32][k8];
            acc[t] = __builtin_amdgcn_mfma_f32_32x32x16_bf16(a_hi, b_hi, acc[t], 0, 0, 0);
            acc[t] = __builtin_amdgcn_mfma_f32_32x32x16_bf16(a_lo, b_hi, acc[t], 0, 0, 0);
            acc[t] = __builtin_amdgcn_mfma_f32_32x32x16_bf16(a_hi, b_lo, acc[t], 0, 0, 0);
        }
    }

    // ---- selection over four 32-column quarters (candidates in index order)
    // Quarter qt = global c-tile qt, owned by waves with (w>>1)==(qt>>1),
    // local tile (qt&1). qt loop UNROLLED: acc indices compile-time constant.
#pragma unroll
    for (int qt = 0; qt < 4; ++qt) {
        __syncthreads();                 // staging/Ds free, prev phase2 done
        if ((w >> 1) == (qt >> 1)) {
#pragma unroll
            for (int r = 0; r < 16; ++r) {
                int row = (w & 1) * 32 + (r & 3) + 8 * (r >> 2) + 4 * (lane >> 5);
                Ds[row][lane & 31] = acc[qt & 1][r];
            }
        }
        __syncthreads();
        // phase1: thread -> (query q = tid&63, chunk ch = tid>>6 of 8 cands)
        {
            int q = tid & 63, ch = tid >> 6;
            float sqq = sqq_s[q];
            float pd[KNN]; int pi[KNN];
#pragma unroll
            for (int j = 0; j < KNN; ++j) { pd[j] = __builtin_inff(); pi[j] = -1; }
#pragma unroll
            for (int j8 = 0; j8 < 8; ++j8) {
                int c = ch * 8 + j8;
                float d = (sqq - 2.0f * Ds[q][c]) + sqc_s[qt * 32 + c];  // inf pad
                if (d < pd[KNN - 1]) {
                    pd[KNN - 1] = d; pi[KNN - 1] = gs + c0 + qt * 32 + c;
#pragma unroll
                    for (int j = KNN - 1; j > 0; --j) {
                        if (pd[j] < pd[j - 1]) {
                            float tf = pd[j]; pd[j] = pd[j - 1]; pd[j - 1] = tf;
                            int tn = pi[j]; pi[j] = pi[j - 1]; pi[j - 1] = tn;
                        }
                    }
                }
            }
#pragma unroll
            for (int j = 0; j < KNN; ++j) { ld[ch][j][q] = pd[j]; li[ch][j][q] = pi[j]; }
        }
        __syncthreads();
        // phase2: 64 threads merge 4 sorted lists (index order; early break)
        if (tid < 64) {
            for (int ch = 0; ch < 4; ++ch) {
#pragma unroll
                for (int j0 = 0; j0 < KNN; ++j0) {
                    float d = ld[ch][j0][tid];
                    if (!(d < td[KNN - 1])) break;   // sorted: rest can't insert
                    int id = li[ch][j0][tid];
                    td[KNN - 1] = d; ti[KNN - 1] = id;
#pragma unroll
                    for (int j = KNN - 1; j > 0; --j) {
                        if (td[j] < td[j - 1]) {
                            float tf = td[j]; td[j] = td[j - 1]; td[j - 1] = tf;
                            int tn = ti[j]; ti[j] = ti[j - 1]; ti[j - 1] = tn;
                        }
                    }
                }
            }
        }
    }

    if (tid < nq) {
        int q = gs + q0 + tid;
        size_t base = ((size_t)q * NSPL + split) * KNN;
#pragma unroll
        for (int j = 0; j < KNN; ++j) { pk_d[base + j] = td[j]; pk_i[base + j] = ti[j]; }
    }
}

// ---------------------------------------------------------------- merge + deg + W-transpose
// blocks 0..127: merge partial lists (64 q each). blocks 128..199: build
// bf16 W0^T/W1^T (n-major) into the dead xl region for out_kernel's MFMA
// B-fragments (fused here to avoid an extra dispatch).
__global__ __launch_bounds__(64) void merge_kernel(
    const float* __restrict__ pk_d, const int* __restrict__ pk_i,
    int* __restrict__ edges, int* __restrict__ deg,
    const float* __restrict__ W0, const float* __restrict__ W1,
    unsigned short* __restrict__ wt)
{
    __shared__ float wtile[32][33];
    int tid = threadIdx.x;
    if (blockIdx.x >= 128) {             // ---- W transpose path
        int wid = blockIdx.x - 128;      // 0..71
        int mat = wid / 36, rem2 = wid % 36;
        int k0 = (rem2 / 6) * 32, n0 = (rem2 % 6) * 32;
        const float* W = mat ? W1 : W0;
#pragma unroll
        for (int p = 0; p < 4; ++p) {
            int idx = p * 64 + tid;
            int k = idx >> 3, n4 = (idx & 7) * 4;
            *(float4*)&wtile[k][n4] =
                *(const float4*)(W + (size_t)(k0 + k) * CF + n0 + n4);
        }
        __syncthreads();
#pragma unroll
        for (int p = 0; p < 4; ++p) {
            int idx = p * 64 + tid;
            int n = idx >> 3, k4 = (idx & 7) * 4;
            ushort4 h;
            h.x = f2bf(wtile[k4 + 0][n]); h.y = f2bf(wtile[k4 + 1][n]);
            h.z = f2bf(wtile[k4 + 2][n]); h.w = f2bf(wtile[k4 + 3][n]);
            *(ushort4*)(wt + (size_t)mat * 36864 + (size_t)(n0 + n) * CF + k0 + k4) = h;
        }
        return;
    }
    int q = blockIdx.x * 64 + tid;
    float td[KNN]; int ti[KNN];
#pragma unroll
    for (int j = 0; j < KNN; ++j) { td[j] = __builtin_inff(); ti[j] = -1; }
    for (int s = 0; s < NSPL; ++s) {       // split order = index order (stable)
        size_t base = ((size_t)q * NSPL + s) * KNN;
#pragma unroll
        for (int j0 = 0; j0 < KNN; ++j0) {
            float d = pk_d[base + j0];
            if (!(d < td[KNN - 1])) break;   // lists sorted: rest can't insert
            int id = pk_i[base + j0];
            td[KNN - 1] = d; ti[KNN - 1] = id;
#pragma unroll
            for (int j = KNN - 1; j > 0; --j) {
                if (td[j] < td[j - 1]) {
                    float tf = td[j]; td[j] = td[j - 1]; td[j - 1] = tf;
                    int tn = ti[j]; ti[j] = ti[j - 1]; ti[j - 1] = tn;
                }
            }
        }
    }
#pragma unroll
    for (int j = 0; j < KNN; ++j) {
        int id = ti[j];                   // -1 <=> invalid (d == inf)
        edges[q * KNN + j] = id;
        if (id >= 0 && id != q) atomicAdd(&deg[id], 1);
    }
}

// ---------------------------------------------------------------- fused Tx1 + out GEMM (MFMA)
// One block per 16-row stripe (512 blocks). out = A0@W0 + A1@W1 + bias via
// mfma_f32_16x16x32_bf16, K=384 fused. A-frag: A[m=lane&15][k=quad*8+j]
// (row-major LDS, rows padded to 200 -> 2-way banks = free). B-frag:
// W^T[n=lane&15][k] row-major from the precomputed wt. C/D (m89-verified):
// col=lane&15, row=(lane>>4)*4+reg. Wave w owns n-tiles {3w..3w+2}.
__global__ __launch_bounds__(256, 2) void out_kernel(
    const unsigned short* __restrict__ xh, const unsigned short* __restrict__ wt,
    const int* __restrict__ edges, const int* __restrict__ deg,
    const float* __restrict__ bias, float* __restrict__ out)
{
    __shared__ unsigned short A0s[16][200];     // xf rows   (6400 B, padded)
    __shared__ unsigned short A1s[16][200];     // Tx1 rows  (6400 B, padded)
    __shared__ unsigned short Wts[2][CF][32];   // W^T k-slice (24576 B)
    __shared__ float coef_s[16][KNN];
    __shared__ int   nb_s[16][KNN];

    int r0 = blockIdx.x * 16;
    int tid = threadIdx.x;

    // stage xf rows (bf16 copy): 16 x 24 uint4 = 384
    for (int t = tid; t < 384; t += 256) {
        int i = t / 24, c8 = (t % 24) * 8;
        *(uint4*)&A0s[i][c8] = *(const uint4*)(xh + (size_t)(r0 + i) * CF + c8);
    }
    // coefficients: one (row, edge) per thread
    if (tid < 16 * KNN) {
        int i = tid / KNN, j = tid % KNN;
        int q = r0 + i;
        int id = edges[q * KNN + j];
        float cf = 0.0f; int s = q;
        if (id >= 0 && id != q) { cf = -disf(deg[id]) * disf(deg[q]); s = id; }
        coef_s[i][j] = cf; nb_s[i][j] = s;
    }
    __syncthreads();
    // gather Tx1 rows from bf16 -> bf16 pairs: 1536 pairs
    for (int e = tid; e < 16 * CF / 2; e += 256) {
        int i = e / 96, c2 = (e % 96) * 2;
        float a0 = 0.0f, a1 = 0.0f;
#pragma unroll
        for (int t = 0; t < KNN; ++t) {
            const unsigned short* row = xh + (size_t)nb_s[i][t] * CF + c2;
            float cf = coef_s[i][t];
            a0 = fmaf(cf, bf2f(row[0]), a0);
            a1 = fmaf(cf, bf2f(row[1]), a1);
        }
        ushort2 h; h.x = f2bf(a0); h.y = f2bf(a1);
        *(ushort2*)&A1s[i][c2] = h;
    }

    int lane = tid & 63, w = tid >> 6;
    int m = lane & 15;                   // A row / B col index
    int kq = (lane >> 4) * 8;            // k offset within 32-slice
    f32x4 acc[3];
#pragma unroll
    for (int t = 0; t < 3; ++t)
#pragma unroll
        for (int r = 0; r < 4; ++r) acc[t][r] = 0.0f;

    for (int kt = 0; kt < 6; ++kt) {     // K=192 in 32-slices, both mats fused
        __syncthreads();                 // kt=0: A1s ready; else Wts consumed
#pragma unroll
        for (int p = 0; p < 6; ++p) {    // stage Wts: 1536 uint4
            int f = p * 256 + tid;
            int mat = f / 768, n = (f % 768) / 4, k16 = (f % 4) * 8;
            *(uint4*)&Wts[mat][n][k16] =
                *(const uint4*)(wt + (size_t)mat * 36864 + (size_t)n * CF + kt * 32 + k16);
        }
        __syncthreads();
        v8bf a0 = *(const v8bf*)&A0s[m][kt * 32 + kq];
        v8bf a1 = *(const v8bf*)&A1s[m][kt * 32 + kq];
#pragma unroll
        for (int t3 = 0; t3 < 3; ++t3) {
            int n0 = w * 48 + t3 * 16;
            v8bf w0 = *(const v8bf*)&Wts[0][n0 + m][kq];
            v8bf w1 = *(const v8bf*)&Wts[1][n0 + m][kq];
            acc[t3] = __builtin_amdgcn_mfma_f32_16x16x32_bf16(a0, w0, acc[t3], 0, 0, 0);
            acc[t3] = __builtin_amdgcn_mfma_f32_16x16x32_bf16(a1, w1, acc[t3], 0, 0, 0);
        }
    }

    int col = lane & 15, rb = (lane >> 4) * 4;
#pragma unroll
    for (int t3 = 0; t3 < 3; ++t3) {
        int n0 = w * 48 + t3 * 16;
        float bv = bias[n0 + col];
#pragma unroll
        for (int r = 0; r < 4; ++r)
            out[(size_t)(r0 + rb + r) * CF + n0 + col] = acc[t3][r] + bv;
    }
}

// ---------------------------------------------------------------- launch
extern "C" void kernel_launch(void* const* d_in, const int* in_sizes, int n_in,
                              void* d_out, int out_size, void* d_ws, size_t ws_size,
                              hipStream_t stream)
{
    const float* x    = (const float*)d_in[0];
    const float* W0   = (const float*)d_in[1];
    const float* W1   = (const float*)d_in[2];
    const float* bias = (const float*)d_in[3];
    float* out = (float*)d_out;

    // Workspace: 6,651,904 B (known-safe total).
    char* ws = (char*)d_ws;
    unsigned short* xh = (unsigned short*)ws; ws += (size_t)NN * CF * 2;  // 3,145,728
    unsigned short* xl = (unsigned short*)ws; ws += (size_t)NN * CF * 2;  // 3,145,728
    float* sq    = (float*)ws;  ws += (size_t)NN * 4;        //    32,768
    int*   deg   = (int*)ws;    ws += (size_t)NN * 4;        //    32,768
    int*   edges = (int*)ws;    ws += (size_t)NN * KNN * 4;  //   294,912

    // xl is dead after knn -> reuse its space for bf16 W0^T/W1^T (147 KB).
    unsigned short* wt = xl;

    // Partial top-k lists live in d_out (4.72 MB of its 6.29 MB); d_out is
    // fully overwritten by out_kernel afterwards, every call.
    float* pk_d = out;                                       // NN*NSPL*KNN
    int*   pk_i = (int*)(out + (size_t)NN * NSPL * KNN);     // NN*NSPL*KNN

    hipLaunchKernelGGL(transpose_kernel, dim3(8, 16), dim3(256), 0, stream,
                       x, xh, xl, sq, deg);
    hipLaunchKernelGGL(knn_kernel, dim3(1152), dim3(256), 0, stream,
                       xh, xl, sq, pk_d, pk_i);
    hipLaunchKernelGGL(merge_kernel, dim3(200), dim3(64), 0, stream,
                       pk_d, pk_i, edges, deg, W0, W1, wt);
    hipLaunchKernelGGL(out_kernel, dim3(512), dim3(256), 0, stream,
                       xh, wt, edges, deg, bias, out);
}